// Round 11
// baseline (370.670 us; speedup 1.0000x reference)
//
#include <hip/hip_runtime.h>
#include <hip/hip_fp16.h>

// GCN: h0 = relu(c_dst ⊙ Agg(c_src ⊙ x @ W0) + b0); h1 = same with W1; out = h1 @ Wc + bc
// R10: (1) aggregate inner loop uses a 2-level fp16 pairwise tree (__hadd2) before fp32
//      accumulate — 28 vs 40 VALU per 8 edges. (2) k_finalize stages each bucket's edges
//      in LDS (cap 8192, global fallback) — one 6.4 MB ebuf read instead of two.

#define PB 256          // partition blocks
#define BSHIFT 8        // bucket = node >> 8 (256 nodes/bucket)
#define FCAP 8192       // finalize LDS edge cap (mean 4096, sd ~64 for uniform dst)

typedef _Float16 f16x8 __attribute__((ext_vector_type(8)));
typedef float f32x4 __attribute__((ext_vector_type(4)));

#define H2(u) (*(__half2*)&(u))

// ---------------- Phase A: bucket counts (src and dst) ----------------

__global__ __launch_bounds__(256) void k_count(const int* __restrict__ src, const int* __restrict__ dst,
                                               int E, int per_blk, int NB,
                                               int* __restrict__ cntT, int* __restrict__ cntT2) {
  __shared__ int cnt[512];
  __shared__ int cnt2[512];
  for (int i = threadIdx.x; i < NB; i += 256) { cnt[i] = 0; cnt2[i] = 0; }
  __syncthreads();
  int e0 = blockIdx.x * per_blk, e1 = min(E, e0 + per_blk);
  for (int e = e0 + threadIdx.x; e < e1; e += 256) {
    atomicAdd(&cnt[dst[e] >> BSHIFT], 1);
    atomicAdd(&cnt2[src[e] >> BSHIFT], 1);
  }
  __syncthreads();
  for (int i = threadIdx.x; i < NB; i += 256) {
    cntT[i * PB + blockIdx.x] = cnt[i];
    cntT2[i * PB + blockIdx.x] = cnt2[i];
  }
}

// exclusive scan of each bucket's 256 per-block counts (works on concatenated tables)
__global__ __launch_bounds__(256) void k_scanblk(const int* __restrict__ cntT, int* __restrict__ offsT,
                                                 int* __restrict__ total) {
  __shared__ int s[256];
  int b = blockIdx.x, t = threadIdx.x;
  int v = cntT[b * PB + t];
  s[t] = v;
  __syncthreads();
  for (int off = 1; off < 256; off <<= 1) {
    int x = (t >= off) ? s[t - off] : 0;
    __syncthreads();
    s[t] += x;
    __syncthreads();
  }
  offsT[b * PB + t] = s[t] - v;
  if (t == 255) total[b] = s[255];
}

__global__ __launch_bounds__(512) void k_scantot(const int* __restrict__ total, int NB, int E,
                                                 int* __restrict__ bbase, int* __restrict__ row_ptr, int N) {
  __shared__ int s[512];
  int t = threadIdx.x;
  int v = (t < NB) ? total[t] : 0;
  s[t] = v;
  __syncthreads();
  for (int off = 1; off < 512; off <<= 1) {
    int x = (t >= off) ? s[t - off] : 0;
    __syncthreads();
    s[t] += x;
    __syncthreads();
  }
  if (t < NB) bbase[t] = s[t] - v;
  if (t == 0) {
    bbase[NB] = E;
    if (row_ptr) row_ptr[N] = E;
  }
}

// ---------------- Phase A: partition scatter (dst-sorted ebuf + src-bucketed srcrel bytes) ----------------

__global__ __launch_bounds__(256) void k_partition(const int* __restrict__ src, const int* __restrict__ dst,
                                                   int E, int per_blk, int NB,
                                                   const int* __restrict__ offsT, const int* __restrict__ bbase,
                                                   const int* __restrict__ offsT2, const int* __restrict__ sbase,
                                                   unsigned* __restrict__ ebuf, unsigned char* __restrict__ sbuf,
                                                   int src_bits) {
  __shared__ int cur[512];
  __shared__ int cur2[512];
  for (int i = threadIdx.x; i < NB; i += 256) {
    cur[i] = bbase[i] + offsT[i * PB + blockIdx.x];
    cur2[i] = sbase[i] + offsT2[i * PB + blockIdx.x];
  }
  __syncthreads();
  int e0 = blockIdx.x * per_blk, e1 = min(E, e0 + per_blk);
  for (int e = e0 + threadIdx.x; e < e1; e += 256) {
    int d = dst[e], s = src[e];
    int pos = atomicAdd(&cur[d >> BSHIFT], 1);
    ebuf[pos] = ((unsigned)(d & ((1 << BSHIFT) - 1)) << src_bits) | (unsigned)s;
    int pos2 = atomicAdd(&cur2[s >> BSHIFT], 1);
    sbuf[pos2] = (unsigned char)(s & ((1 << BSHIFT) - 1));
  }
}

// ---------------- Phase B: per-dst-bucket finalize -> row_ptr, c_dst, col_idx (BYTE offsets) ----------------
// Single global read of ebuf: staged into LDS (cap FCAP, fallback to global past the cap).

__global__ __launch_bounds__(256) void k_finalize(const unsigned* __restrict__ ebuf, const int* __restrict__ bbase,
                                                  int N, int src_bits, int* __restrict__ row_ptr,
                                                  float* __restrict__ c_dst, int* __restrict__ col_idx) {
  __shared__ unsigned eb[FCAP];
  __shared__ int cnt[256];
  __shared__ int s[256];
  __shared__ int cur[256];
  int b = blockIdx.x, t = threadIdx.x;
  int r0 = bbase[b], r1 = bbase[b + 1];
  int len = r1 - r0;
  cnt[t] = 0;
  __syncthreads();
  for (int i = t; i < len; i += 256) {
    unsigned e = ebuf[r0 + i];
    if (i < FCAP) eb[i] = e;
    atomicAdd(&cnt[e >> src_bits], 1);
  }
  __syncthreads();
  int v = cnt[t];
  s[t] = v;
  __syncthreads();
  for (int off = 1; off < 256; off <<= 1) {
    int x = (t >= off) ? s[t - off] : 0;
    __syncthreads();
    s[t] += x;
    __syncthreads();
  }
  int ex = s[t] - v;
  cur[t] = ex;
  int node = (b << BSHIFT) + t;
  if (node < N) {
    row_ptr[node] = r0 + ex;
    c_dst[node] = rsqrtf((float)max(v, 1));
  }
  __syncthreads();
  unsigned smask = (1u << src_bits) - 1u;
  for (int i = t; i < len; i += 256) {
    unsigned e = (i < FCAP) ? eb[i] : ebuf[r0 + i];
    int pos = r0 + atomicAdd(&cur[e >> src_bits], 1);
    col_idx[pos] = (int)((e & smask) << 8);   // byte offset into fp16 h rows (256 B/row)
  }
}

// ---------------- Phase B: per-src-bucket histogram -> c_src ----------------

__global__ __launch_bounds__(256) void k_finalize_src(const unsigned char* __restrict__ sbuf,
                                                      const int* __restrict__ sbase, int N,
                                                      float* __restrict__ c_src) {
  __shared__ int cnt[256];
  int b = blockIdx.x, t = threadIdx.x;
  int r0 = sbase[b], r1 = sbase[b + 1];
  cnt[t] = 0;
  __syncthreads();
  for (int i = r0 + t; i < r1; i += 256) atomicAdd(&cnt[sbuf[i]], 1);
  __syncthreads();
  int node = (b << BSHIFT) + t;
  if (node < N) c_src[node] = rsqrtf((float)max(cnt[t], 1));
}

// ---------------- MFMA GEMM: out[m][n] = (sum_k A[m][k]*sc[m]*W[k][n]) -> fp16 ----------------

__device__ __forceinline__ f16x8 load_af(const float* arow, int off, float csc) {
  float4 a0 = *(const float4*)(arow + off);
  float4 a1 = *(const float4*)(arow + off + 4);
  f16x8 v;
  v[0] = (_Float16)(a0.x * csc);
  v[1] = (_Float16)(a0.y * csc);
  v[2] = (_Float16)(a0.z * csc);
  v[3] = (_Float16)(a0.w * csc);
  v[4] = (_Float16)(a1.x * csc);
  v[5] = (_Float16)(a1.y * csc);
  v[6] = (_Float16)(a1.z * csc);
  v[7] = (_Float16)(a1.w * csc);
  return v;
}

__device__ __forceinline__ f16x8 load_af(const __half* arow, int off, float csc) {
  f16x8 v = *(const f16x8*)(arow + off);
  _Float16 c = (_Float16)csc;
#pragma unroll
  for (int j = 0; j < 8; j++) v[j] = v[j] * c;
  return v;
}

template <typename AT>
__global__ __launch_bounds__(256) void k_gemm_mfma(const AT* __restrict__ A, const float* __restrict__ W,
                                                   const float* __restrict__ scale, __half* __restrict__ out, int N) {
  __shared__ _Float16 Wt[128][136];
  int t = threadIdx.x;
  {
    int nlow = t & 15;
    int kplow = t >> 4;
#pragma unroll
    for (int j = 0; j < 32; j++) {
      int n = nlow + 16 * (j & 7);
      int kp = kplow + 16 * (j >> 3);
      float w0 = W[(size_t)(2 * kp) * 128 + n];
      float w1 = W[(size_t)(2 * kp + 1) * 128 + n];
      __half2 h2 = __floats2half2_rn(w0, w1);
      *(__half2*)&Wt[n][2 * kp] = h2;
    }
  }
  __syncthreads();

  int wave = t >> 6;
  int lane = t & 63;
  int li = lane & 15;
  int q = lane >> 4;

#pragma unroll
  for (int s2 = 0; s2 < 2; s2++) {
    int m0 = (blockIdx.x * 2 + s2) * 128 + wave * 32;
    if (m0 >= N) break;

    int mrow[2];
    float csc[2];
    bool mok[2];
    const AT* arow[2];
#pragma unroll
    for (int s = 0; s < 2; s++) {
      mrow[s] = m0 + s * 16 + li;
      mok[s] = mrow[s] < N;
      csc[s] = mok[s] ? scale[mrow[s]] : 0.f;
      arow[s] = A + (size_t)(mok[s] ? mrow[s] : 0) * 128;
    }

    f32x4 acc[2][8];
#pragma unroll
    for (int s = 0; s < 2; s++)
#pragma unroll
      for (int nt = 0; nt < 8; nt++) acc[s][nt] = (f32x4){0.f, 0.f, 0.f, 0.f};

#pragma unroll
    for (int kc = 0; kc < 128; kc += 32) {
      f16x8 af[2];
#pragma unroll
      for (int s = 0; s < 2; s++) af[s] = load_af(arow[s], kc + q * 8, csc[s]);
#pragma unroll
      for (int nt = 0; nt < 8; nt++) {
        f16x8 wf = *(const f16x8*)&Wt[nt * 16 + li][kc + q * 8];
        acc[0][nt] = __builtin_amdgcn_mfma_f32_16x16x32_f16(wf, af[0], acc[0][nt], 0, 0, 0);
        acc[1][nt] = __builtin_amdgcn_mfma_f32_16x16x32_f16(wf, af[1], acc[1][nt], 0, 0, 0);
      }
    }

#pragma unroll
    for (int s = 0; s < 2; s++) {
      if (!mok[s]) continue;
      size_t rb = (size_t)mrow[s] * 128;
#pragma unroll
      for (int nt = 0; nt < 8; nt++) {
        __half2 p0 = __floats2half2_rn(acc[s][nt][0], acc[s][nt][1]);
        __half2 p1 = __floats2half2_rn(acc[s][nt][2], acc[s][nt][3]);
        uint2 qv;
        qv.x = *(unsigned*)&p0;
        qv.y = *(unsigned*)&p1;
        *(uint2*)&out[rb + nt * 16 + q * 4] = qv;
      }
    }
  }
}

// ---------------- Sparse aggregation: fp16 rows in, fp16 out ----------------
// Wave per node; half-waves take contiguous sub-ranges; unroll 8 edges/half with a
// 2-level fp16 pairwise tree before fp32 accumulate. col_idx = byte offsets.

__device__ __forceinline__ void acc_h2(float4& a, __half2 hx, __half2 hy) {
  float2 f0 = __half22float2(hx);
  float2 f1 = __half22float2(hy);
  a.x += f0.x; a.y += f0.y; a.z += f1.x; a.w += f1.y;
}

__device__ __forceinline__ void acc_pair(float4& a, uint2 qa, uint2 qb) {
  acc_h2(a, __hadd2(H2(qa.x), H2(qb.x)), __hadd2(H2(qa.y), H2(qb.y)));
}

__device__ __forceinline__ void acc_one(float4& a, uint2 q) {
  acc_h2(a, H2(q.x), H2(q.y));
}

__global__ __launch_bounds__(256) void k_aggregate_h(const __half* __restrict__ hin, const int* __restrict__ rp,
                                                     const int* __restrict__ ci, const float* __restrict__ c_dst,
                                                     const float* __restrict__ bias, __half* __restrict__ hout, int N) {
  int v = blockIdx.x * 4 + (threadIdx.x >> 6);
  if (v >= N) return;
  int half_id = (threadIdx.x >> 5) & 1;
  int f4 = (threadIdx.x & 31) * 4;
  const char* hb = (const char*)hin + f4 * 2;
  int p0 = rp[v], pe = rp[v + 1];
  int mid = p0 + ((pe - p0 + 1) >> 1);
  int p = half_id ? mid : p0;
  int pend = half_id ? pe : mid;
  float4 a0 = make_float4(0.f, 0.f, 0.f, 0.f);
  float4 a1 = make_float4(0.f, 0.f, 0.f, 0.f);
  for (; p + 7 < pend; p += 8) {
    int u0 = ci[p];
    int u1 = ci[p + 1];
    int u2 = ci[p + 2];
    int u3 = ci[p + 3];
    int u4 = ci[p + 4];
    int u5 = ci[p + 5];
    int u6 = ci[p + 6];
    int u7 = ci[p + 7];
    uint2 q0 = *(const uint2*)(hb + (size_t)(unsigned)u0);
    uint2 q1 = *(const uint2*)(hb + (size_t)(unsigned)u1);
    uint2 q2 = *(const uint2*)(hb + (size_t)(unsigned)u2);
    uint2 q3 = *(const uint2*)(hb + (size_t)(unsigned)u3);
    uint2 q4 = *(const uint2*)(hb + (size_t)(unsigned)u4);
    uint2 q5 = *(const uint2*)(hb + (size_t)(unsigned)u5);
    uint2 q6 = *(const uint2*)(hb + (size_t)(unsigned)u6);
    uint2 q7 = *(const uint2*)(hb + (size_t)(unsigned)u7);
    // level 1 (fp16, <=1 ulp each)
    __half2 x0 = __hadd2(H2(q0.x), H2(q1.x)), y0 = __hadd2(H2(q0.y), H2(q1.y));
    __half2 x1 = __hadd2(H2(q2.x), H2(q3.x)), y1 = __hadd2(H2(q2.y), H2(q3.y));
    __half2 x2 = __hadd2(H2(q4.x), H2(q5.x)), y2 = __hadd2(H2(q4.y), H2(q5.y));
    __half2 x3 = __hadd2(H2(q6.x), H2(q7.x)), y3 = __hadd2(H2(q6.y), H2(q7.y));
    // level 2 + fp32 accumulate
    acc_h2(a0, __hadd2(x0, x1), __hadd2(y0, y1));
    acc_h2(a1, __hadd2(x2, x3), __hadd2(y2, y3));
  }
  for (; p + 1 < pend; p += 2) {
    int u0 = ci[p];
    int u1 = ci[p + 1];
    uint2 q0 = *(const uint2*)(hb + (size_t)(unsigned)u0);
    uint2 q1 = *(const uint2*)(hb + (size_t)(unsigned)u1);
    acc_pair(a0, q0, q1);
  }
  if (p < pend) {
    uint2 q = *(const uint2*)(hb + (size_t)(unsigned)ci[p]);
    acc_one(a0, q);
  }
  a0.x += a1.x; a0.y += a1.y; a0.z += a1.z; a0.w += a1.w;
  a0.x += __shfl_xor(a0.x, 32);
  a0.y += __shfl_xor(a0.y, 32);
  a0.z += __shfl_xor(a0.z, 32);
  a0.w += __shfl_xor(a0.w, 32);
  if (half_id == 0) {
    float cd = c_dst[v];
    float4 b = *(const float4*)&bias[f4];
    float4 o;
    o.x = fmaxf(fmaf(a0.x, cd, b.x), 0.f);
    o.y = fmaxf(fmaf(a0.y, cd, b.y), 0.f);
    o.z = fmaxf(fmaf(a0.z, cd, b.z), 0.f);
    o.w = fmaxf(fmaf(a0.w, cd, b.w), 0.f);
    __half2 p0h = __floats2half2_rn(o.x, o.y);
    __half2 p1h = __floats2half2_rn(o.z, o.w);
    uint2 qv;
    qv.x = *(unsigned*)&p0h;
    qv.y = *(unsigned*)&p1h;
    *(uint2*)&hout[(size_t)v * 128 + f4] = qv;
  }
}

// ---------------- Classifier: out[N,47] = h(fp16) @ Wc + bc, register-tiled ----------------

__global__ __launch_bounds__(256) void k_classifier(const __half* __restrict__ h, const float* __restrict__ Wc,
                                                    const float* __restrict__ bc, float* __restrict__ out, int N) {
  __shared__ float hs[256][33];
  __shared__ float Ws[32][48];
  __shared__ float bs[48];
  int t = threadIdx.x;
  int row0 = blockIdx.x * 256;
  int tc = t & 3;
  int tm = t >> 2;
  if (t < 47) bs[t] = bc[t];
  if (t == 255) bs[47] = 0.f;

  float acc[4][12];
#pragma unroll
  for (int g = 0; g < 4; g++)
#pragma unroll
    for (int j = 0; j < 12; j++) acc[g][j] = 0.f;

  for (int kb = 0; kb < 128; kb += 32) {
#pragma unroll
    for (int i = 0; i < 4; i++) {
      int f = t + i * 256;
      int r = f >> 2;
      int c8 = (f & 3) * 8;
      int g = row0 + r;
      f16x8 v;
      if (g < N) v = *(const f16x8*)&h[(size_t)g * 128 + kb + c8];
      else {
#pragma unroll
        for (int j = 0; j < 8; j++) v[j] = (_Float16)0.f;
      }
#pragma unroll
      for (int j = 0; j < 8; j++) hs[r][c8 + j] = (float)v[j];
    }
#pragma unroll
    for (int i = 0; i < 6; i++) {
      int f = t + i * 256;
      int k = f / 48;
      int c = f - k * 48;
      Ws[k][c] = (c < 47) ? Wc[(size_t)(kb + k) * 47 + c] : 0.f;
    }
    __syncthreads();
#pragma unroll 4
    for (int k = 0; k < 32; k++) {
      float4 w0 = *(const float4*)&Ws[k][tc * 12];
      float4 w1 = *(const float4*)&Ws[k][tc * 12 + 4];
      float4 w2 = *(const float4*)&Ws[k][tc * 12 + 8];
      float a0 = hs[tm][k];
      float a1 = hs[tm + 64][k];
      float a2 = hs[tm + 128][k];
      float a3 = hs[tm + 192][k];
      float a[4] = {a0, a1, a2, a3};
#pragma unroll
      for (int g = 0; g < 4; g++) {
        acc[g][0] = fmaf(a[g], w0.x, acc[g][0]);
        acc[g][1] = fmaf(a[g], w0.y, acc[g][1]);
        acc[g][2] = fmaf(a[g], w0.z, acc[g][2]);
        acc[g][3] = fmaf(a[g], w0.w, acc[g][3]);
        acc[g][4] = fmaf(a[g], w1.x, acc[g][4]);
        acc[g][5] = fmaf(a[g], w1.y, acc[g][5]);
        acc[g][6] = fmaf(a[g], w1.z, acc[g][6]);
        acc[g][7] = fmaf(a[g], w1.w, acc[g][7]);
        acc[g][8] = fmaf(a[g], w2.x, acc[g][8]);
        acc[g][9] = fmaf(a[g], w2.y, acc[g][9]);
        acc[g][10] = fmaf(a[g], w2.z, acc[g][10]);
        acc[g][11] = fmaf(a[g], w2.w, acc[g][11]);
      }
    }
    __syncthreads();
  }
#pragma unroll
  for (int g = 0; g < 4; g++) {
    int r = row0 + tm + 64 * g;
    if (r < N) {
#pragma unroll
      for (int j = 0; j < 12; j++) {
        int c = tc * 12 + j;
        if (c < 47) out[(size_t)r * 47 + c] = acc[g][j] + bs[c];
      }
    }
  }
}

// ---------------- launch ----------------

extern "C" void kernel_launch(void* const* d_in, const int* in_sizes, int n_in,
                              void* d_out, int out_size, void* d_ws, size_t ws_size,
                              hipStream_t stream) {
  const float* x  = (const float*)d_in[0];
  const int* edges = (const int*)d_in[1];
  const float* W0 = (const float*)d_in[2];
  const float* b0 = (const float*)d_in[3];
  const float* W1 = (const float*)d_in[4];
  const float* b1 = (const float*)d_in[5];
  const float* Wc = (const float*)d_in[6];
  const float* bc = (const float*)d_in[7];
  float* out = (float*)d_out;

  int N = in_sizes[0] / 128;
  int E = in_sizes[1] / 2;
  const int* src = edges;
  const int* dst = edges + E;

  int NB = (N + ((1 << BSHIFT) - 1)) >> BSHIFT;   // 391 (<=512 required)
  int src_bits = 0;
  while ((1 << src_bits) < N) src_bits++;          // 17
  int per_blk = (E + PB - 1) / PB;

  char* base = (char*)d_ws;
  size_t off = 0;
  auto alloc = [&](size_t bytes) -> void* {
    void* p = base + off;
    off += (bytes + 255) & ~(size_t)255;
    return p;
  };
  float* c_src = (float*)alloc((size_t)N * 4);
  float* c_dst = (float*)alloc((size_t)N * 4);
  int* row_ptr = (int*)alloc((size_t)(N + 1) * 4);
  int* col_idx = (int*)alloc((size_t)E * 4);
  __half* h0h = (__half*)alloc((size_t)N * 128 * 2);   // GEMM outputs (fp16, 25.6 MB)
  __half* h1h = (__half*)alloc((size_t)N * 128 * 2);   // aggregate outputs (fp16, 25.6 MB)

  // build-time scratch carved out of h1h (dead until first k_aggregate writes it)
  char* hb = (char*)h1h;
  unsigned* ebuf = (unsigned*)hb;            hb += (size_t)E * 4;
  unsigned char* sbuf = (unsigned char*)hb;  hb += ((size_t)E + 255) & ~(size_t)255;
  int* cntT = (int*)hb;                      hb += (size_t)2 * NB * PB * 4;   // [dst | src]
  int* offsT = (int*)hb;                     hb += (size_t)2 * NB * PB * 4;
  int* total = (int*)hb;                     hb += (size_t)2 * NB * 4;
  int* bbase = (int*)hb;                     hb += (size_t)(NB + 1) * 4;
  int* sbase = (int*)hb;                     hb += (size_t)(NB + 1) * 4;
  int* cntT2 = cntT + (size_t)NB * PB;
  int* offsT2 = offsT + (size_t)NB * PB;
  int* total2 = total + NB;

  k_count<<<PB, 256, 0, stream>>>(src, dst, E, per_blk, NB, cntT, cntT2);
  k_scanblk<<<2 * NB, 256, 0, stream>>>(cntT, offsT, total);
  k_scantot<<<1, 512, 0, stream>>>(total, NB, E, bbase, row_ptr, N);
  k_scantot<<<1, 512, 0, stream>>>(total2, NB, E, sbase, (int*)nullptr, N);
  k_partition<<<PB, 256, 0, stream>>>(src, dst, E, per_blk, NB, offsT, bbase, offsT2, sbase,
                                      ebuf, sbuf, src_bits);
  k_finalize<<<NB, 256, 0, stream>>>(ebuf, bbase, N, src_bits, row_ptr, c_dst, col_idx);
  k_finalize_src<<<NB, 256, 0, stream>>>(sbuf, sbase, N, c_src);

  int strips = (N + 127) / 128;
  int gblocks = (strips + 1) / 2;
  k_gemm_mfma<float><<<gblocks, 256, 0, stream>>>(x, W0, c_src, h0h, N);
  k_aggregate_h<<<(N + 3) / 4, 256, 0, stream>>>(h0h, row_ptr, col_idx, c_dst, b0, h1h, N);
  k_gemm_mfma<__half><<<gblocks, 256, 0, stream>>>(h1h, W1, c_src, h0h, N);
  k_aggregate_h<<<(N + 3) / 4, 256, 0, stream>>>(h0h, row_ptr, col_idx, c_dst, b1, h1h, N);
  k_classifier<<<(N + 255) / 256, 256, 0, stream>>>(h1h, Wc, bc, out, N);
}